// Round 2
// baseline (301.819 us; speedup 1.0000x reference)
//
#include <hip/hip_runtime.h>
#include <stdint.h>

// GumbelVQ forward, MI355X — round 18: fused stats (last-block election) +
// 4096 blocks (2 rows x 2 code-chains) + bit-exact gumbel op shaves.
//
// R17 post-mortem: argmax is VALU-issue-bound at sustained clock (~1.2-1.3 GHz
// effective; VALUBusy 91%). Remaining costs: 43us tail (stats kernel + launch
// gaps), 9% idle issue (occupancy 53% at 2048 blocks), ~2 shaveable ops/cand.
// This round: (1) last-block-done election runs the entropy/usage/commit
// finalize inside the argmax dispatch (device-scope atomics, agent-scope
// loads); (2) grid back to 4096 blocks — each block does 2 rows x 2 code
// chains (same 4-chain ILP through the proven threefry asm); (3) u-construct
// via one v_alignbit (bit-identical), -l1 via input modifier (bit-identical).
// The candidate value v = dot + gumbel keeps R17's exact fma/add order — zero
// numeric risk on the argmax.
//
//   d_out (float[73731]):
//     [0..65535]     z_q f32 (B,D,H,W)          — argmax epilogue
//     [65536..73727] indices as f32 values      — argmax epilogue
//     [73728..73730] commit, perplexity, usage  — 73728 doubles as commit accum
// Inputs (float32): z_e (8,8,32,32), embedding (8192,8), proj_w (8192,8).

#define NCODES 8192
#define NROWS  8192

__device__ int g_hist[NCODES];
__device__ int g_done;

// ---------------- threefry-2x32, key (0,42), 4 interleaved chains ----------
// Counter for (row n, code k) is c = n*8192 + k (hi word = 0). JAX
// partitionable path: bits = o0 ^ o1 of threefry((0,42), (0, c)).
// Inputs %8..%11 must hold c + 42 (ks1 pre-added). Outputs %0..%3 = o0^o1.
// rotl(x,r) == v_alignbit_b32(x, x, 32-r).

#define TF4_R1 \
  "v_mov_b32 %4, %8\n" "v_mov_b32 %5, %9\n" \
  "v_mov_b32 %6, %10\n" "v_mov_b32 %7, %11\n" \
  "v_alignbit_b32 %0, %8, %8, 19\n" "v_alignbit_b32 %1, %9, %9, 19\n" \
  "v_alignbit_b32 %2, %10, %10, 19\n" "v_alignbit_b32 %3, %11, %11, 19\n" \
  "v_xor_b32 %0, %0, %4\n" "v_xor_b32 %1, %1, %5\n" \
  "v_xor_b32 %2, %2, %6\n" "v_xor_b32 %3, %3, %7\n"

#define TF4_ADD \
  "v_add_u32 %4, %4, %0\n" "v_add_u32 %5, %5, %1\n" \
  "v_add_u32 %6, %6, %2\n" "v_add_u32 %7, %7, %3\n"

#define TF4_ADD3_42 \
  "v_add3_u32 %4, %4, %0, 42\n" "v_add3_u32 %5, %5, %1, 42\n" \
  "v_add3_u32 %6, %6, %2, 42\n" "v_add3_u32 %7, %7, %3, 42\n"

#define TF4_ROT(s) \
  "v_alignbit_b32 %0, %0, %0, " #s "\n" "v_alignbit_b32 %1, %1, %1, " #s "\n" \
  "v_alignbit_b32 %2, %2, %2, " #s "\n" "v_alignbit_b32 %3, %3, %3, " #s "\n"

#define TF4_XOR \
  "v_xor_b32 %0, %0, %4\n" "v_xor_b32 %1, %1, %5\n" \
  "v_xor_b32 %2, %2, %6\n" "v_xor_b32 %3, %3, %7\n"

#define TF4_AX1(lit) \
  "v_add_u32 %0, " #lit ", %0\n" "v_add_u32 %1, " #lit ", %1\n" \
  "v_add_u32 %2, " #lit ", %2\n" "v_add_u32 %3, " #lit ", %3\n"

#define TF4_AX0(lit) \
  "v_add_u32 %4, " #lit ", %4\n" "v_add_u32 %5, " #lit ", %5\n" \
  "v_add_u32 %6, " #lit ", %6\n" "v_add_u32 %7, " #lit ", %7\n"

#define TF4_RN(s)  TF4_ADD     TF4_ROT(s) TF4_XOR
#define TF4_RN3(s) TF4_ADD3_42 TF4_ROT(s) TF4_XOR

// gumbel = -ln(-ln u) = C - ln2*log2(-log2 u), C = -ln2*log2(ln2).
#define GVQ_C   0.36651292058166435f
#define GVQ_LN2 0.69314718055994530942f
__device__ __forceinline__ float gvq18_gumbel(uint32_t bits) {
    // (0x7F<<23)|(bits>>9) == (bits>>9)|0x3f800000 : one v_alignbit_b32
    float u = __uint_as_float(__builtin_amdgcn_alignbit(0x7Fu, bits, 9u)) - 1.0f;
    float l1 = __builtin_amdgcn_logf(u);            // log2(u) < 0 strictly
    float l2 = __builtin_amdgcn_logf(-l1);          // negate folds to modifier
    return fmaf(-GVQ_LN2, l2, GVQ_C);
}

__global__ __launch_bounds__(256) void gvq18_init(float* out) {
    const int k = blockIdx.x * 256 + threadIdx.x;
    g_hist[k] = 0;
    if (k == 0) { out[73728] = 0.0f; g_done = 0; }
}

#define DOT8(zz, wa, wb) \
    fmaf(zz[7], wb.w, fmaf(zz[6], wb.z, fmaf(zz[5], wb.y, fmaf(zz[4], wb.x, \
    fmaf(zz[3], wa.w, fmaf(zz[2], wa.z, fmaf(zz[1], wa.y, zz[0] * wa.x)))))))

// 2 rows/block, 2 code-chains/thread (codes k=tid+512i and k+256), 16 iters.
__global__ __launch_bounds__(256, 5) void gvq18_argmax(const float* __restrict__ z_e,
                                                       const float* __restrict__ proj_w,
                                                       const float* __restrict__ emb,
                                                       float* __restrict__ out) {
    __shared__ float sv[2][256];
    __shared__ int   sj[2][256];
    __shared__ float ssq[2];
    __shared__ int   is_last;
    const int tid = threadIdx.x;
    const int n0 = blockIdx.x * 2;
    const int n1 = n0 + 1;

    float z0[8], z1[8];
#pragma unroll
    for (int d = 0; d < 8; ++d) {
        z0[d] = z_e[(n0 >> 10) * 8192 + d * 1024 + (n0 & 1023)];
        z1[d] = z_e[(n1 >> 10) * 8192 + d * 1024 + (n1 & 1023)];
    }

    // counters with ks1 (=42) pre-added; chains (n0,kA),(n0,kB),(n1,kA),(n1,kB)
    uint32_t ca = ((uint32_t)n0 << 13) + (uint32_t)tid + 42u;
    uint32_t cb = ca + 256u;
    uint32_t cc = ca + 8192u;
    uint32_t cd = ca + 8448u;

    const float4* wr = (const float4*)proj_w;
    float bA0 = -INFINITY, bB0 = -INFINITY, bA1 = -INFINITY, bB1 = -INFINITY;
    int iA0 = 0, iB0 = 0, iA1 = 0, iB1 = 0;
    int k = tid;

    for (int i = 0; i < 16; ++i) {
        const int base = (i << 10) + 2 * tid;       // float4 index of code kA
        float4 wa0 = wr[base];
        float4 wb0 = wr[base + 1];
        float4 wa1 = wr[base + 512];                // code kA+256
        float4 wb1 = wr[base + 513];

        float dA0 = DOT8(z0, wa0, wb0);
        float dB0 = DOT8(z0, wa1, wb1);
        float dA1 = DOT8(z1, wa0, wb0);
        float dB1 = DOT8(z1, wa1, wb1);

        uint32_t o0, o1, o2, o3, t0, t1, t2, t3;
        asm(TF4_R1                                   // G1: rot 13,15,26,6
            TF4_RN(17) TF4_RN(6) TF4_RN(26)
            TF4_AX1(0x1BD11BF1)                      // x1 += ks2+1
            TF4_RN3(15) TF4_RN(3) TF4_RN(16) TF4_RN(8)  // G2 (x0+=42 folded)
            TF4_AX0(0x1BD11BF0) TF4_AX1(2)           // x0 += ks2; x1 += 2
            TF4_RN(19) TF4_RN(17) TF4_RN(6) TF4_RN(26)  // G3 (x0+=0 free)
            TF4_AX1(45)                              // x1 += 45
            TF4_RN(15) TF4_RN(3) TF4_RN(16) TF4_RN(8)   // G4
            TF4_AX1(0x1BD11BF4)                      // x1 += ks2+4
            TF4_RN3(19) TF4_RN(17) TF4_RN(6) TF4_RN(26) // G5 (x0+=42 folded)
            TF4_AX0(0x1BD11BF0) TF4_AX1(5)           // final x0 += ks2; x1 += 5
            TF4_XOR                                  // out = x1 ^ x0
            : "=&v"(o0), "=&v"(o1), "=&v"(o2), "=&v"(o3),
              "=&v"(t0), "=&v"(t1), "=&v"(t2), "=&v"(t3)
            : "v"(ca), "v"(cb), "v"(cc), "v"(cd));
        (void)t0; (void)t1; (void)t2; (void)t3;

        float vA0 = dA0 + gvq18_gumbel(o0);
        float vB0 = dB0 + gvq18_gumbel(o1);
        float vA1 = dA1 + gvq18_gumbel(o2);
        float vB1 = dB1 + gvq18_gumbel(o3);

        if (vA0 > bA0) { bA0 = vA0; iA0 = k; }      // strict > : first max wins
        if (vB0 > bB0) { bB0 = vB0; iB0 = k + 256; }
        if (vA1 > bA1) { bA1 = vA1; iA1 = k; }
        if (vB1 > bB1) { bB1 = vB1; iB1 = k + 256; }

        ca += 512u; cb += 512u; cc += 512u; cd += 512u;
        k += 512;
    }

    // merge the two code-chains per row; exact ties -> smaller index
    float best0 = bA0; int bi0 = iA0;
    if (bB0 > best0 || (bB0 == best0 && iB0 < bi0)) { best0 = bB0; bi0 = iB0; }
    float best1 = bA1; int bi1 = iA1;
    if (bB1 > best1 || (bB1 == best1 && iB1 < bi1)) { best1 = bB1; bi1 = iB1; }

    sv[0][tid] = best0; sj[0][tid] = bi0;
    sv[1][tid] = best1; sj[1][tid] = bi1;
    __syncthreads();
    for (int s = 128; s > 0; s >>= 1) {
        if (tid < s) {
#pragma unroll
            for (int r = 0; r < 2; ++r) {
                float va = sv[r][tid + s];
                int   ja = sj[r][tid + s];
                if (va > sv[r][tid] || (va == sv[r][tid] && ja < sj[r][tid])) {
                    sv[r][tid] = va; sj[r][tid] = ja;
                }
            }
        }
        __syncthreads();
    }

    if (tid < 2) {
        const int n = n0 + tid;
        const int idx = sj[tid][0];
        out[65536 + n] = (float)idx;
        atomicAdd(&g_hist[idx], 1);
        float zz[8];
#pragma unroll
        for (int d = 0; d < 8; ++d) zz[d] = (tid == 0) ? z0[d] : z1[d];
        const float4* ep = (const float4*)(emb + idx * 8);
        float4 ea = ep[0], eb = ep[1];
        float e[8] = {ea.x, ea.y, ea.z, ea.w, eb.x, eb.y, eb.z, eb.w};
        const int b = n >> 10, r = n & 1023;
        float sq = 0.0f;
#pragma unroll
        for (int d = 0; d < 8; ++d) {
            out[b * 8192 + d * 1024 + r] = e[d];     // z_q (B,D,H,W)
            float diff = zz[d] - e[d];
            sq = fmaf(diff, diff, sq);
        }
        ssq[tid] = sq;
    }
    __syncthreads();
    if (tid == 0) {
        atomicAdd(out + 73728, ssq[0] + ssq[1]);     // commit partial
        __threadfence();                              // release hist+commit
        int old = __hip_atomic_fetch_add(&g_done, 1, __ATOMIC_ACQ_REL,
                                         __HIP_MEMORY_SCOPE_AGENT);
        is_last = (old == 4095);
    }
    __syncthreads();

    if (is_last) {
        // final block: entropy/usage from g_hist, finalize commit
        float h = 0.0f; int used = 0;
        for (int kk = tid; kk < NCODES; kk += 256) {
            int c = __hip_atomic_load(&g_hist[kk], __ATOMIC_RELAXED,
                                      __HIP_MEMORY_SCOPE_AGENT);
            float avg = (float)c * (1.0f / 8192.0f);
            h += avg * logf(avg + 1e-10f);
            used += (c > 0) ? 1 : 0;
        }
        sv[0][tid] = h; sj[0][tid] = used;
        __syncthreads();
        for (int s = 128; s > 0; s >>= 1) {
            if (tid < s) { sv[0][tid] += sv[0][tid + s]; sj[0][tid] += sj[0][tid + s]; }
            __syncthreads();
        }
        if (tid == 0) {
            float accum = __hip_atomic_load(out + 73728, __ATOMIC_RELAXED,
                                            __HIP_MEMORY_SCOPE_AGENT);
            out[73728] = 0.25f * accum * (1.0f / 65536.0f);   // commit loss
            out[73729] = expf(-sv[0][0]);                     // perplexity
            out[73730] = (float)sj[0][0] * (1.0f / 8192.0f);  // usage
        }
    }
}

extern "C" void kernel_launch(void* const* d_in, const int* in_sizes, int n_in,
                              void* d_out, int out_size, void* d_ws, size_t ws_size,
                              hipStream_t stream) {
    const float* z_e   = (const float*)d_in[0];
    const float* emb   = (const float*)d_in[1];
    const float* projw = (const float*)d_in[2];
    float* out = (float*)d_out;

    gvq18_init  <<<32,   256, 0, stream>>>(out);
    gvq18_argmax<<<4096, 256, 0, stream>>>(z_e, projw, emb, out);
}

// Round 3
// 249.701 us; speedup vs baseline: 1.2087x; 1.2087x over previous
//
#include <hip/hip_runtime.h>
#include <stdint.h>

// GumbelVQ forward, MI355X — round 19: R17 argmax loop (proven 169us) +
// single-dispatch graph (fused stats via last-block election, init kernel
// eliminated via self-cleaning device globals) + bit-identical gumbel shaves.
//
// R18 post-mortem: 2rows x 2chains doubled proj_w traffic and broke load
// pipelining (VALUBusy 91->60). The R17 loop structure (4 rows/block, one
// contiguous 32B load + pointer bump per iter) is the proven issue-bound
// core — restored verbatim. Tail analysis: ~43us of the total is dispatch
// overhead, not kernel bodies -> collapse to ONE dispatch. g_hist/g_done/
// g_commit are .bss (zeroed at module load); the elected last block re-zeros
// them after use so every subsequent graph replay starts clean.
//
//   d_out (float[73731]):
//     [0..65535]     z_q f32 (B,D,H,W)
//     [65536..73727] indices as f32 values
//     [73728..73730] commit, perplexity, usage
// Inputs (float32): z_e (8,8,32,32), embedding (8192,8), proj_w (8192,8).

#define NCODES 8192
#define NROWS  8192
#define NBLOCKS 2048

__device__ int   g_hist[NCODES];
__device__ int   g_done;
__device__ float g_commit;

// ---------------- threefry-2x32, key (0,42), 4 interleaved chains ----------
// Counter for (row n, code k) is c = n*8192 + k (hi word = 0). JAX
// partitionable path: bits = o0 ^ o1 of threefry((0,42), (0, c)).
// Inputs %8..%11 must hold c + 42 (ks1 pre-added). Outputs %0..%3 = o0^o1.
// rotl(x,r) == v_alignbit_b32(x, x, 32-r).

#define TF4_R1 \
  "v_mov_b32 %4, %8\n" "v_mov_b32 %5, %9\n" \
  "v_mov_b32 %6, %10\n" "v_mov_b32 %7, %11\n" \
  "v_alignbit_b32 %0, %8, %8, 19\n" "v_alignbit_b32 %1, %9, %9, 19\n" \
  "v_alignbit_b32 %2, %10, %10, 19\n" "v_alignbit_b32 %3, %11, %11, 19\n" \
  "v_xor_b32 %0, %0, %4\n" "v_xor_b32 %1, %1, %5\n" \
  "v_xor_b32 %2, %2, %6\n" "v_xor_b32 %3, %3, %7\n"

#define TF4_ADD \
  "v_add_u32 %4, %4, %0\n" "v_add_u32 %5, %5, %1\n" \
  "v_add_u32 %6, %6, %2\n" "v_add_u32 %7, %7, %3\n"

#define TF4_ADD3_42 \
  "v_add3_u32 %4, %4, %0, 42\n" "v_add3_u32 %5, %5, %1, 42\n" \
  "v_add3_u32 %6, %6, %2, 42\n" "v_add3_u32 %7, %7, %3, 42\n"

#define TF4_ROT(s) \
  "v_alignbit_b32 %0, %0, %0, " #s "\n" "v_alignbit_b32 %1, %1, %1, " #s "\n" \
  "v_alignbit_b32 %2, %2, %2, " #s "\n" "v_alignbit_b32 %3, %3, %3, " #s "\n"

#define TF4_XOR \
  "v_xor_b32 %0, %0, %4\n" "v_xor_b32 %1, %1, %5\n" \
  "v_xor_b32 %2, %2, %6\n" "v_xor_b32 %3, %3, %7\n"

#define TF4_AX1(lit) \
  "v_add_u32 %0, " #lit ", %0\n" "v_add_u32 %1, " #lit ", %1\n" \
  "v_add_u32 %2, " #lit ", %2\n" "v_add_u32 %3, " #lit ", %3\n"

#define TF4_AX0(lit) \
  "v_add_u32 %4, " #lit ", %4\n" "v_add_u32 %5, " #lit ", %5\n" \
  "v_add_u32 %6, " #lit ", %6\n" "v_add_u32 %7, " #lit ", %7\n"

#define TF4_RN(s)  TF4_ADD     TF4_ROT(s) TF4_XOR
#define TF4_RN3(s) TF4_ADD3_42 TF4_ROT(s) TF4_XOR

// gumbel = -ln(-ln u) = C - ln2*log2(-log2 u), C = -ln2*log2(ln2).
#define GVQ_C   0.36651292058166435f
#define GVQ_LN2 0.69314718055994530942f
__device__ __forceinline__ float gvq19_gumbel(uint32_t bits) {
    // (0x7F<<23)|(bits>>9) == (bits>>9)|0x3f800000 : one v_alignbit_b32
    float u = __uint_as_float(__builtin_amdgcn_alignbit(0x7Fu, bits, 9u)) - 1.0f;
    float l1 = __builtin_amdgcn_logf(u);            // log2(u) < 0 strictly
    float l2 = __builtin_amdgcn_logf(-l1);          // negate folds to modifier
    return fmaf(-GVQ_LN2, l2, GVQ_C);
}

#define DOT8(zz) \
    fmaf(zz[7], wb.w, fmaf(zz[6], wb.z, fmaf(zz[5], wb.y, fmaf(zz[4], wb.x, \
    fmaf(zz[3], wa.w, fmaf(zz[2], wa.z, fmaf(zz[1], wa.y, zz[0] * wa.x)))))))

// 4 rows/block, thread-per-code stride 256, 32 iterations (R17 structure).
__global__ __launch_bounds__(256, 4) void gvq19_argmax(const float* __restrict__ z_e,
                                                       const float* __restrict__ proj_w,
                                                       const float* __restrict__ emb,
                                                       float* __restrict__ out) {
    __shared__ float sv[4][256];
    __shared__ int   sj[4][256];
    __shared__ float ssq[4];
    __shared__ int   is_last;
    const int tid = threadIdx.x;
    const int n0 = blockIdx.x * 4;                  // rows n0..n0+3

    float z0[8], z1[8], z2[8], z3[8];
#pragma unroll
    for (int d = 0; d < 8; ++d) {
        const int nA = n0 + 0, nB = n0 + 1, nC = n0 + 2, nD = n0 + 3;
        z0[d] = z_e[(nA >> 10) * 8192 + d * 1024 + (nA & 1023)];
        z1[d] = z_e[(nB >> 10) * 8192 + d * 1024 + (nB & 1023)];
        z2[d] = z_e[(nC >> 10) * 8192 + d * 1024 + (nC & 1023)];
        z3[d] = z_e[(nD >> 10) * 8192 + d * 1024 + (nD & 1023)];
    }

    // counters with ks1 (=42) pre-added
    uint32_t ca = ((uint32_t)(n0 + 0) << 13) + (uint32_t)tid + 42u;
    uint32_t cb = ((uint32_t)(n0 + 1) << 13) + (uint32_t)tid + 42u;
    uint32_t cc = ((uint32_t)(n0 + 2) << 13) + (uint32_t)tid + 42u;
    uint32_t cd = ((uint32_t)(n0 + 3) << 13) + (uint32_t)tid + 42u;

    const float4* p = ((const float4*)proj_w) + 2 * tid;
    float best0 = -INFINITY, best1 = -INFINITY, best2 = -INFINITY, best3 = -INFINITY;
    int bi0 = 0, bi1 = 0, bi2 = 0, bi3 = 0;
    int k = tid;

    for (int i = 0; i < 32; ++i) {
        float4 wa = p[0];
        float4 wb = p[1];
        p += 512;                                   // 256 codes * 2 float4

        float d0 = DOT8(z0);
        float d1 = DOT8(z1);
        float d2 = DOT8(z2);
        float d3 = DOT8(z3);

        uint32_t o0, o1, o2, o3, t0, t1, t2, t3;
        asm(TF4_R1                                   // G1: rot 13,15,26,6
            TF4_RN(17) TF4_RN(6) TF4_RN(26)
            TF4_AX1(0x1BD11BF1)                      // x1 += ks2+1
            TF4_RN3(15) TF4_RN(3) TF4_RN(16) TF4_RN(8)  // G2 (x0+=42 folded)
            TF4_AX0(0x1BD11BF0) TF4_AX1(2)           // x0 += ks2; x1 += 2
            TF4_RN(19) TF4_RN(17) TF4_RN(6) TF4_RN(26)  // G3 (x0+=0 free)
            TF4_AX1(45)                              // x1 += 45
            TF4_RN(15) TF4_RN(3) TF4_RN(16) TF4_RN(8)   // G4
            TF4_AX1(0x1BD11BF4)                      // x1 += ks2+4
            TF4_RN3(19) TF4_RN(17) TF4_RN(6) TF4_RN(26) // G5 (x0+=42 folded)
            TF4_AX0(0x1BD11BF0) TF4_AX1(5)           // final x0 += ks2; x1 += 5
            TF4_XOR                                  // out = x1 ^ x0
            : "=&v"(o0), "=&v"(o1), "=&v"(o2), "=&v"(o3),
              "=&v"(t0), "=&v"(t1), "=&v"(t2), "=&v"(t3)
            : "v"(ca), "v"(cb), "v"(cc), "v"(cd));
        (void)t0; (void)t1; (void)t2; (void)t3;

        float v0 = d0 + gvq19_gumbel(o0);
        float v1 = d1 + gvq19_gumbel(o1);
        float v2 = d2 + gvq19_gumbel(o2);
        float v3 = d3 + gvq19_gumbel(o3);

        if (v0 > best0) { best0 = v0; bi0 = k; }    // strict > : first max wins
        if (v1 > best1) { best1 = v1; bi1 = k; }
        if (v2 > best2) { best2 = v2; bi2 = k; }
        if (v3 > best3) { best3 = v3; bi3 = k; }

        ca += 256u; cb += 256u; cc += 256u; cd += 256u;
        k += 256;
    }

    sv[0][tid] = best0; sj[0][tid] = bi0;
    sv[1][tid] = best1; sj[1][tid] = bi1;
    sv[2][tid] = best2; sj[2][tid] = bi2;
    sv[3][tid] = best3; sj[3][tid] = bi3;
    __syncthreads();
    for (int s = 128; s > 0; s >>= 1) {
        if (tid < s) {
#pragma unroll
            for (int r = 0; r < 4; ++r) {
                float va = sv[r][tid + s];
                int   ja = sj[r][tid + s];
                if (va > sv[r][tid] || (va == sv[r][tid] && ja < sj[r][tid])) {
                    sv[r][tid] = va; sj[r][tid] = ja;
                }
            }
        }
        __syncthreads();
    }

    if (tid < 4) {
        const int n = n0 + tid;
        const int idx = sj[tid][0];
        out[65536 + n] = (float)idx;
        atomicAdd(&g_hist[idx], 1);
        float zz[8];
#pragma unroll
        for (int d = 0; d < 8; ++d) {
            zz[d] = (tid == 0) ? z0[d] : (tid == 1) ? z1[d]
                  : (tid == 2) ? z2[d] : z3[d];
        }
        const float4* ep = (const float4*)(emb + idx * 8);
        float4 ea = ep[0], eb = ep[1];
        float e[8] = {ea.x, ea.y, ea.z, ea.w, eb.x, eb.y, eb.z, eb.w};
        const int b = n >> 10, r = n & 1023;
        float sq = 0.0f;
#pragma unroll
        for (int d = 0; d < 8; ++d) {
            out[b * 8192 + d * 1024 + r] = e[d];     // z_q (B,D,H,W)
            float diff = zz[d] - e[d];
            sq = fmaf(diff, diff, sq);
        }
        ssq[tid] = sq;
    }
    __syncthreads();
    if (tid == 0) {
        atomicAdd(&g_commit, ssq[0] + ssq[1] + ssq[2] + ssq[3]);
        __threadfence();                              // release hist+commit
        int old = __hip_atomic_fetch_add(&g_done, 1, __ATOMIC_ACQ_REL,
                                         __HIP_MEMORY_SCOPE_AGENT);
        is_last = (old == NBLOCKS - 1);
    }
    __syncthreads();

    if (is_last) {
        // Elected final block: entropy/usage from g_hist, finalize commit,
        // then self-clean the device globals for the next graph replay.
        float h = 0.0f; int used = 0;
        for (int kk = tid; kk < NCODES; kk += 256) {
            int c = __hip_atomic_load(&g_hist[kk], __ATOMIC_RELAXED,
                                      __HIP_MEMORY_SCOPE_AGENT);
            float avg = (float)c * (1.0f / 8192.0f);
            h += avg * logf(avg + 1e-10f);
            used += (c > 0) ? 1 : 0;
            g_hist[kk] = 0;                          // same thread read it
        }
        sv[0][tid] = h; sj[0][tid] = used;
        __syncthreads();
        for (int s = 128; s > 0; s >>= 1) {
            if (tid < s) { sv[0][tid] += sv[0][tid + s]; sj[0][tid] += sj[0][tid + s]; }
            __syncthreads();
        }
        if (tid == 0) {
            float accum = __hip_atomic_load(&g_commit, __ATOMIC_RELAXED,
                                            __HIP_MEMORY_SCOPE_AGENT);
            out[73728] = 0.25f * accum * (1.0f / 65536.0f);   // commit loss
            out[73729] = expf(-sv[0][0]);                     // perplexity
            out[73730] = (float)sj[0][0] * (1.0f / 8192.0f);  // usage
            g_commit = 0.0f;                                  // self-clean
            g_done = 0;
        }
    }
}

extern "C" void kernel_launch(void* const* d_in, const int* in_sizes, int n_in,
                              void* d_out, int out_size, void* d_ws, size_t ws_size,
                              hipStream_t stream) {
    const float* z_e   = (const float*)d_in[0];
    const float* emb   = (const float*)d_in[1];
    const float* projw = (const float*)d_in[2];
    float* out = (float*)d_out;

    gvq19_argmax<<<NBLOCKS, 256, 0, stream>>>(z_e, projw, emb, out);
}

// Round 4
// 227.565 us; speedup vs baseline: 1.3263x; 1.0973x over previous
//
#include <hip/hip_runtime.h>
#include <stdint.h>

// GumbelVQ forward, MI355X — round 20: fence-free election + tied-operand
// threefry asm (kills R1 movs) + launch_bounds(256,6) + SGPR-index select.
//
// R19 post-mortem: dur x VALUBusy is invariant (~152 us-busy) across R17/18/19
// -> VALU work identical; R19's +40us was pure stall from __threadfence
// (L2-writeback class) + ACQ_REL acquire-invalidate at 2048 block exits
// disturbing co-resident blocks (FETCH unchanged, busy 91->72). Fix: the
// pre-election __syncthreads already drains vmcnt(0) per-wave (compiler emits
// full waitcnt before s_barrier), and hist/commit are device-scope atomics
// completing at the device-coherent point — so a RELAXED g_done fetch_add
// after the barrier is a correct, cache-neutral election. tid0 issues one
// s_waitcnt vmcnt(0) for its own commit-atomic before the bump.
//
// Shaves vs R17 loop (all bit-identical semantics):
//  - asm round 1: x0 == input counter reg ("+v" tied) -> no 4x v_mov; counter
//    recomputed per iter as base + (i<<8) (same add count as the old bump).
//  - best-index tracked as iter i; k=(i<<8)+tid reconstructed at shared-write
//    (tie compare still on full k). Deletes per-iter k bump.
//  - launch_bounds(256,6): 80 VGPRs fits cap 85 -> 6 blocks/CU (75% nominal).
//
//   d_out (float[73731]):
//     [0..65535]     z_q f32 (B,D,H,W)
//     [65536..73727] indices as f32 values
//     [73728..73730] commit, perplexity, usage
// Inputs (float32): z_e (8,8,32,32), embedding (8192,8), proj_w (8192,8).

#define NCODES 8192
#define NROWS  8192
#define NBLOCKS 2048

__device__ int   g_hist[NCODES];
__device__ int   g_done;
__device__ float g_commit;

// ---------------- threefry-2x32, key (0,42), 4 interleaved chains ----------
// Counter for (row n, code k) is c = n*8192 + k (hi word = 0). JAX
// partitionable path: bits = o0 ^ o1 of threefry((0,42), (0, c)).
// Operand map: %0-%3 = x1 ("=&v" outs, final value = o0^o1),
//              %4-%7 = x0 ("+v" in-outs, enter holding c + 42).
// rotl(x,r) == v_alignbit_b32(x, x, 32-r).

#define TF4_R1T \
  "v_alignbit_b32 %0, %4, %4, 19\n" "v_alignbit_b32 %1, %5, %5, 19\n" \
  "v_alignbit_b32 %2, %6, %6, 19\n" "v_alignbit_b32 %3, %7, %7, 19\n" \
  "v_xor_b32 %0, %0, %4\n" "v_xor_b32 %1, %1, %5\n" \
  "v_xor_b32 %2, %2, %6\n" "v_xor_b32 %3, %3, %7\n"

#define TF4_ADD \
  "v_add_u32 %4, %4, %0\n" "v_add_u32 %5, %5, %1\n" \
  "v_add_u32 %6, %6, %2\n" "v_add_u32 %7, %7, %3\n"

#define TF4_ADD3_42 \
  "v_add3_u32 %4, %4, %0, 42\n" "v_add3_u32 %5, %5, %1, 42\n" \
  "v_add3_u32 %6, %6, %2, 42\n" "v_add3_u32 %7, %7, %3, 42\n"

#define TF4_ROT(s) \
  "v_alignbit_b32 %0, %0, %0, " #s "\n" "v_alignbit_b32 %1, %1, %1, " #s "\n" \
  "v_alignbit_b32 %2, %2, %2, " #s "\n" "v_alignbit_b32 %3, %3, %3, " #s "\n"

#define TF4_XOR \
  "v_xor_b32 %0, %0, %4\n" "v_xor_b32 %1, %1, %5\n" \
  "v_xor_b32 %2, %2, %6\n" "v_xor_b32 %3, %3, %7\n"

#define TF4_AX1(lit) \
  "v_add_u32 %0, " #lit ", %0\n" "v_add_u32 %1, " #lit ", %1\n" \
  "v_add_u32 %2, " #lit ", %2\n" "v_add_u32 %3, " #lit ", %3\n"

#define TF4_AX0(lit) \
  "v_add_u32 %4, " #lit ", %4\n" "v_add_u32 %5, " #lit ", %5\n" \
  "v_add_u32 %6, " #lit ", %6\n" "v_add_u32 %7, " #lit ", %7\n"

#define TF4_RN(s)  TF4_ADD     TF4_ROT(s) TF4_XOR
#define TF4_RN3(s) TF4_ADD3_42 TF4_ROT(s) TF4_XOR

// gumbel = -ln(-ln u) = C - ln2*log2(-log2 u), C = -ln2*log2(ln2).
#define GVQ_C   0.36651292058166435f
#define GVQ_LN2 0.69314718055994530942f
__device__ __forceinline__ float gvq20_gumbel(uint32_t bits) {
    // (0x7F<<23)|(bits>>9) == (bits>>9)|0x3f800000 : one v_alignbit_b32
    float u = __uint_as_float(__builtin_amdgcn_alignbit(0x7Fu, bits, 9u)) - 1.0f;
    float l1 = __builtin_amdgcn_logf(u);            // log2(u) < 0 strictly
    float l2 = __builtin_amdgcn_logf(-l1);          // negate folds to modifier
    return fmaf(-GVQ_LN2, l2, GVQ_C);
}

#define DOT8(zz) \
    fmaf(zz[7], wb.w, fmaf(zz[6], wb.z, fmaf(zz[5], wb.y, fmaf(zz[4], wb.x, \
    fmaf(zz[3], wa.w, fmaf(zz[2], wa.z, fmaf(zz[1], wa.y, zz[0] * wa.x)))))))

// 4 rows/block, thread-per-code stride 256, 32 iterations (R17 structure).
__global__ __launch_bounds__(256, 6) void gvq20_argmax(const float* __restrict__ z_e,
                                                       const float* __restrict__ proj_w,
                                                       const float* __restrict__ emb,
                                                       float* __restrict__ out) {
    __shared__ float sv[4][256];
    __shared__ int   sj[4][256];
    __shared__ float ssq[4];
    __shared__ int   is_last;
    const int tid = threadIdx.x;
    const int n0 = blockIdx.x * 4;                  // rows n0..n0+3

    float z0[8], z1[8], z2[8], z3[8];
#pragma unroll
    for (int d = 0; d < 8; ++d) {
        const int nA = n0 + 0, nB = n0 + 1, nC = n0 + 2, nD = n0 + 3;
        z0[d] = z_e[(nA >> 10) * 8192 + d * 1024 + (nA & 1023)];
        z1[d] = z_e[(nB >> 10) * 8192 + d * 1024 + (nB & 1023)];
        z2[d] = z_e[(nC >> 10) * 8192 + d * 1024 + (nC & 1023)];
        z3[d] = z_e[(nD >> 10) * 8192 + d * 1024 + (nD & 1023)];
    }

    // per-chain counter bases with ks1 (=42) pre-added
    const uint32_t ba = ((uint32_t)(n0 + 0) << 13) + (uint32_t)tid + 42u;
    const uint32_t bb = ((uint32_t)(n0 + 1) << 13) + (uint32_t)tid + 42u;
    const uint32_t bc = ((uint32_t)(n0 + 2) << 13) + (uint32_t)tid + 42u;
    const uint32_t bd = ((uint32_t)(n0 + 3) << 13) + (uint32_t)tid + 42u;

    const float4* p = ((const float4*)proj_w) + 2 * tid;
    float best0 = -INFINITY, best1 = -INFINITY, best2 = -INFINITY, best3 = -INFINITY;
    int bi0 = 0, bi1 = 0, bi2 = 0, bi3 = 0;

    for (int i = 0; i < 32; ++i) {
        float4 wa = p[0];
        float4 wb = p[1];
        p += 512;                                   // 256 codes * 2 float4

        float d0 = DOT8(z0);
        float d1 = DOT8(z1);
        float d2 = DOT8(z2);
        float d3 = DOT8(z3);

        const uint32_t soff = (uint32_t)(i << 8);   // wave-uniform
        uint32_t xa = ba + soff, xb = bb + soff, xc = bc + soff, xd = bd + soff;
        uint32_t o0, o1, o2, o3;
        asm(TF4_R1T                                  // G1 r1: x1=rotl(c,13)^c
            TF4_RN(17) TF4_RN(6) TF4_RN(26)          // G1 r2-4 (rot 15,26,6)
            TF4_AX1(0x1BD11BF1)                      // x1 += ks2+1
            TF4_RN3(15) TF4_RN(3) TF4_RN(16) TF4_RN(8)  // G2 (x0+=42 folded)
            TF4_AX0(0x1BD11BF0) TF4_AX1(2)           // x0 += ks2; x1 += 2
            TF4_RN(19) TF4_RN(17) TF4_RN(6) TF4_RN(26)  // G3 (x0+=0 free)
            TF4_AX1(45)                              // x1 += 45
            TF4_RN(15) TF4_RN(3) TF4_RN(16) TF4_RN(8)   // G4
            TF4_AX1(0x1BD11BF4)                      // x1 += ks2+4
            TF4_RN3(19) TF4_RN(17) TF4_RN(6) TF4_RN(26) // G5 (x0+=42 folded)
            TF4_AX0(0x1BD11BF0) TF4_AX1(5)           // final x0 += ks2; x1 += 5
            TF4_XOR                                  // out = x1 ^ x0
            : "=&v"(o0), "=&v"(o1), "=&v"(o2), "=&v"(o3),
              "+v"(xa), "+v"(xb), "+v"(xc), "+v"(xd));

        float v0 = d0 + gvq20_gumbel(o0);
        float v1 = d1 + gvq20_gumbel(o1);
        float v2 = d2 + gvq20_gumbel(o2);
        float v3 = d3 + gvq20_gumbel(o3);

        if (v0 > best0) { best0 = v0; bi0 = i; }    // strict > : first max wins
        if (v1 > best1) { best1 = v1; bi1 = i; }
        if (v2 > best2) { best2 = v2; bi2 = i; }
        if (v3 > best3) { best3 = v3; bi3 = i; }
    }

    // reconstruct full code index k = (i<<8) + tid (tie compare needs full k)
    sv[0][tid] = best0; sj[0][tid] = (bi0 << 8) + tid;
    sv[1][tid] = best1; sj[1][tid] = (bi1 << 8) + tid;
    sv[2][tid] = best2; sj[2][tid] = (bi2 << 8) + tid;
    sv[3][tid] = best3; sj[3][tid] = (bi3 << 8) + tid;
    __syncthreads();
    for (int s = 128; s > 0; s >>= 1) {
        if (tid < s) {
#pragma unroll
            for (int r = 0; r < 4; ++r) {
                float va = sv[r][tid + s];
                int   ja = sj[r][tid + s];
                if (va > sv[r][tid] || (va == sv[r][tid] && ja < sj[r][tid])) {
                    sv[r][tid] = va; sj[r][tid] = ja;
                }
            }
        }
        __syncthreads();
    }

    if (tid < 4) {
        const int n = n0 + tid;
        const int idx = sj[tid][0];
        out[65536 + n] = (float)idx;
        atomicAdd(&g_hist[idx], 1);                 // device-scope, relaxed
        float zz[8];
#pragma unroll
        for (int d = 0; d < 8; ++d) {
            zz[d] = (tid == 0) ? z0[d] : (tid == 1) ? z1[d]
                  : (tid == 2) ? z2[d] : z3[d];
        }
        const float4* ep = (const float4*)(emb + idx * 8);
        float4 ea = ep[0], eb = ep[1];
        float e[8] = {ea.x, ea.y, ea.z, ea.w, eb.x, eb.y, eb.z, eb.w};
        const int b = n >> 10, r = n & 1023;
        float sq = 0.0f;
#pragma unroll
        for (int d = 0; d < 8; ++d) {
            out[b * 8192 + d * 1024 + r] = e[d];     // z_q (B,D,H,W)
            float diff = zz[d] - e[d];
            sq = fmaf(diff, diff, sq);
        }
        ssq[tid] = sq;
    }
    // Barrier drains each wave's vmcnt to 0 before s_barrier -> all four
    // hist atomics + stores are complete (coherent-point-acked) past here.
    __syncthreads();
    if (tid == 0) {
        atomicAdd(&g_commit, ssq[0] + ssq[1] + ssq[2] + ssq[3]);
        asm volatile("s_waitcnt vmcnt(0)" ::: "memory");   // commit acked
        int old = __hip_atomic_fetch_add(&g_done, 1, __ATOMIC_RELAXED,
                                         __HIP_MEMORY_SCOPE_AGENT);
        is_last = (old == NBLOCKS - 1);
    }
    __syncthreads();

    if (is_last) {
        // Elected final block: entropy/usage from g_hist, finalize commit,
        // then self-clean the device globals for the next graph replay.
        float h = 0.0f; int used = 0;
        for (int kk = tid; kk < NCODES; kk += 256) {
            int c = __hip_atomic_load(&g_hist[kk], __ATOMIC_RELAXED,
                                      __HIP_MEMORY_SCOPE_AGENT);
            float avg = (float)c * (1.0f / 8192.0f);
            h += avg * logf(avg + 1e-10f);
            used += (c > 0) ? 1 : 0;
            g_hist[kk] = 0;                          // kernel-end release flushes
        }
        sv[0][tid] = h; sj[0][tid] = used;
        __syncthreads();
        for (int s = 128; s > 0; s >>= 1) {
            if (tid < s) { sv[0][tid] += sv[0][tid + s]; sj[0][tid] += sj[0][tid + s]; }
            __syncthreads();
        }
        if (tid == 0) {
            float accum = __hip_atomic_load(&g_commit, __ATOMIC_RELAXED,
                                            __HIP_MEMORY_SCOPE_AGENT);
            out[73728] = 0.25f * accum * (1.0f / 65536.0f);   // commit loss
            out[73729] = expf(-sv[0][0]);                     // perplexity
            out[73730] = (float)sj[0][0] * (1.0f / 8192.0f);  // usage
            g_commit = 0.0f;                                  // self-clean
            g_done = 0;
        }
    }
}

extern "C" void kernel_launch(void* const* d_in, const int* in_sizes, int n_in,
                              void* d_out, int out_size, void* d_ws, size_t ws_size,
                              hipStream_t stream) {
    const float* z_e   = (const float*)d_in[0];
    const float* emb   = (const float*)d_in[1];
    const float* projw = (const float*)d_in[2];
    float* out = (float*)d_out;

    gvq20_argmax<<<NBLOCKS, 256, 0, stream>>>(z_e, projw, emb, out);
}

// Round 5
// 212.372 us; speedup vs baseline: 1.4212x; 1.0715x over previous
//
#include <hip/hip_runtime.h>
#include <stdint.h>

// GumbelVQ forward, MI355X — round 21: R17 3-dispatch structure (proven 91%
// VALU-busy) x R20 shaved loop (proven 147us busy-work). No election, no
// fences, launch_bounds(256,5) exactly as the 169us R17 config.
//
// R20 post-mortem: busy-time 155->147us (shaves worked) but stall 9%->22%
// (in-dispatch election drain + (256,6) register squeeze: occ 53->48). Tail
// is harness-fixed (~39-43us regardless of 1 or 3 dispatches) -> fusion is
// worthless; revert to the separate stats kernel. This round = R17 structure
// with only the bit-identical loop shaves swapped in:
//  - tied-operand threefry round 1 (no v_movs)
//  - counter = base + (i<<8) wave-uniform recompute
//  - best-index tracked as 5-bit iter i, k reconstructed at shared-write
//  - gumbel u-construct via one v_alignbit; -l1 via input modifier
//
//   d_out (float[73731]):
//     [0..65535]     z_q f32 (B,D,H,W)
//     [65536..73727] indices as f32 values
//     [73728..73730] commit, perplexity, usage (73728 doubles as accumulator)
// Inputs (float32): z_e (8,8,32,32), embedding (8192,8), proj_w (8192,8).

#define NCODES 8192
#define NROWS  8192
#define NBLOCKS 2048

__device__ int g_hist[NCODES];

// ---------------- threefry-2x32, key (0,42), 4 interleaved chains ----------
// Counter for (row n, code k) is c = n*8192 + k (hi word = 0). JAX
// partitionable path: bits = o0 ^ o1 of threefry((0,42), (0, c)).
// Operand map: %0-%3 = x1 ("=&v" outs, final value = o0^o1),
//              %4-%7 = x0 ("+v" in-outs, enter holding c + 42).
// rotl(x,r) == v_alignbit_b32(x, x, 32-r).

#define TF4_R1T \
  "v_alignbit_b32 %0, %4, %4, 19\n" "v_alignbit_b32 %1, %5, %5, 19\n" \
  "v_alignbit_b32 %2, %6, %6, 19\n" "v_alignbit_b32 %3, %7, %7, 19\n" \
  "v_xor_b32 %0, %0, %4\n" "v_xor_b32 %1, %1, %5\n" \
  "v_xor_b32 %2, %2, %6\n" "v_xor_b32 %3, %3, %7\n"

#define TF4_ADD \
  "v_add_u32 %4, %4, %0\n" "v_add_u32 %5, %5, %1\n" \
  "v_add_u32 %6, %6, %2\n" "v_add_u32 %7, %7, %3\n"

#define TF4_ADD3_42 \
  "v_add3_u32 %4, %4, %0, 42\n" "v_add3_u32 %5, %5, %1, 42\n" \
  "v_add3_u32 %6, %6, %2, 42\n" "v_add3_u32 %7, %7, %3, 42\n"

#define TF4_ROT(s) \
  "v_alignbit_b32 %0, %0, %0, " #s "\n" "v_alignbit_b32 %1, %1, %1, " #s "\n" \
  "v_alignbit_b32 %2, %2, %2, " #s "\n" "v_alignbit_b32 %3, %3, %3, " #s "\n"

#define TF4_XOR \
  "v_xor_b32 %0, %0, %4\n" "v_xor_b32 %1, %1, %5\n" \
  "v_xor_b32 %2, %2, %6\n" "v_xor_b32 %3, %3, %7\n"

#define TF4_AX1(lit) \
  "v_add_u32 %0, " #lit ", %0\n" "v_add_u32 %1, " #lit ", %1\n" \
  "v_add_u32 %2, " #lit ", %2\n" "v_add_u32 %3, " #lit ", %3\n"

#define TF4_AX0(lit) \
  "v_add_u32 %4, " #lit ", %4\n" "v_add_u32 %5, " #lit ", %5\n" \
  "v_add_u32 %6, " #lit ", %6\n" "v_add_u32 %7, " #lit ", %7\n"

#define TF4_RN(s)  TF4_ADD     TF4_ROT(s) TF4_XOR
#define TF4_RN3(s) TF4_ADD3_42 TF4_ROT(s) TF4_XOR

// gumbel = -ln(-ln u) = C - ln2*log2(-log2 u), C = -ln2*log2(ln2).
#define GVQ_C   0.36651292058166435f
#define GVQ_LN2 0.69314718055994530942f
__device__ __forceinline__ float gvq21_gumbel(uint32_t bits) {
    // (0x7F<<23)|(bits>>9) == (bits>>9)|0x3f800000 : one v_alignbit_b32
    float u = __uint_as_float(__builtin_amdgcn_alignbit(0x7Fu, bits, 9u)) - 1.0f;
    float l1 = __builtin_amdgcn_logf(u);            // log2(u) < 0 strictly
    float l2 = __builtin_amdgcn_logf(-l1);          // negate folds to modifier
    return fmaf(-GVQ_LN2, l2, GVQ_C);
}

__global__ __launch_bounds__(1024) void gvq21_init(float* out) {
    const int t = threadIdx.x;
    for (int k = t; k < NCODES; k += 1024) g_hist[k] = 0;
    if (t == 0) out[73728] = 0.0f;                  // commit accumulator
}

#define DOT8(zz) \
    fmaf(zz[7], wb.w, fmaf(zz[6], wb.z, fmaf(zz[5], wb.y, fmaf(zz[4], wb.x, \
    fmaf(zz[3], wa.w, fmaf(zz[2], wa.z, fmaf(zz[1], wa.y, zz[0] * wa.x)))))))

// 4 rows/block, thread-per-code stride 256, 32 iterations (R17 structure).
__global__ __launch_bounds__(256, 5) void gvq21_argmax(const float* __restrict__ z_e,
                                                       const float* __restrict__ proj_w,
                                                       const float* __restrict__ emb,
                                                       float* __restrict__ out) {
    __shared__ float sv[4][256];
    __shared__ int   sj[4][256];
    __shared__ float ssq[4];
    const int tid = threadIdx.x;
    const int n0 = blockIdx.x * 4;                  // rows n0..n0+3

    float z0[8], z1[8], z2[8], z3[8];
#pragma unroll
    for (int d = 0; d < 8; ++d) {
        const int nA = n0 + 0, nB = n0 + 1, nC = n0 + 2, nD = n0 + 3;
        z0[d] = z_e[(nA >> 10) * 8192 + d * 1024 + (nA & 1023)];
        z1[d] = z_e[(nB >> 10) * 8192 + d * 1024 + (nB & 1023)];
        z2[d] = z_e[(nC >> 10) * 8192 + d * 1024 + (nC & 1023)];
        z3[d] = z_e[(nD >> 10) * 8192 + d * 1024 + (nD & 1023)];
    }

    // per-chain counter bases with ks1 (=42) pre-added
    const uint32_t ba = ((uint32_t)(n0 + 0) << 13) + (uint32_t)tid + 42u;
    const uint32_t bb = ((uint32_t)(n0 + 1) << 13) + (uint32_t)tid + 42u;
    const uint32_t bc = ((uint32_t)(n0 + 2) << 13) + (uint32_t)tid + 42u;
    const uint32_t bd = ((uint32_t)(n0 + 3) << 13) + (uint32_t)tid + 42u;

    const float4* p = ((const float4*)proj_w) + 2 * tid;
    float best0 = -INFINITY, best1 = -INFINITY, best2 = -INFINITY, best3 = -INFINITY;
    int bi0 = 0, bi1 = 0, bi2 = 0, bi3 = 0;

    for (int i = 0; i < 32; ++i) {
        float4 wa = p[0];
        float4 wb = p[1];
        p += 512;                                   // 256 codes * 2 float4

        float d0 = DOT8(z0);
        float d1 = DOT8(z1);
        float d2 = DOT8(z2);
        float d3 = DOT8(z3);

        const uint32_t soff = (uint32_t)(i << 8);   // wave-uniform
        uint32_t xa = ba + soff, xb = bb + soff, xc = bc + soff, xd = bd + soff;
        uint32_t o0, o1, o2, o3;
        asm(TF4_R1T                                  // G1 r1: x1=rotl(c,13)^c
            TF4_RN(17) TF4_RN(6) TF4_RN(26)          // G1 r2-4 (rot 15,26,6)
            TF4_AX1(0x1BD11BF1)                      // x1 += ks2+1
            TF4_RN3(15) TF4_RN(3) TF4_RN(16) TF4_RN(8)  // G2 (x0+=42 folded)
            TF4_AX0(0x1BD11BF0) TF4_AX1(2)           // x0 += ks2; x1 += 2
            TF4_RN(19) TF4_RN(17) TF4_RN(6) TF4_RN(26)  // G3 (x0+=0 free)
            TF4_AX1(45)                              // x1 += 45
            TF4_RN(15) TF4_RN(3) TF4_RN(16) TF4_RN(8)   // G4
            TF4_AX1(0x1BD11BF4)                      // x1 += ks2+4
            TF4_RN3(19) TF4_RN(17) TF4_RN(6) TF4_RN(26) // G5 (x0+=42 folded)
            TF4_AX0(0x1BD11BF0) TF4_AX1(5)           // final x0 += ks2; x1 += 5
            TF4_XOR                                  // out = x1 ^ x0
            : "=&v"(o0), "=&v"(o1), "=&v"(o2), "=&v"(o3),
              "+v"(xa), "+v"(xb), "+v"(xc), "+v"(xd));

        float v0 = d0 + gvq21_gumbel(o0);
        float v1 = d1 + gvq21_gumbel(o1);
        float v2 = d2 + gvq21_gumbel(o2);
        float v3 = d3 + gvq21_gumbel(o3);

        if (v0 > best0) { best0 = v0; bi0 = i; }    // strict > : first max wins
        if (v1 > best1) { best1 = v1; bi1 = i; }
        if (v2 > best2) { best2 = v2; bi2 = i; }
        if (v3 > best3) { best3 = v3; bi3 = i; }
    }

    // reconstruct full code index k = (i<<8) + tid (tie compare needs full k)
    sv[0][tid] = best0; sj[0][tid] = (bi0 << 8) + tid;
    sv[1][tid] = best1; sj[1][tid] = (bi1 << 8) + tid;
    sv[2][tid] = best2; sj[2][tid] = (bi2 << 8) + tid;
    sv[3][tid] = best3; sj[3][tid] = (bi3 << 8) + tid;
    __syncthreads();
    for (int s = 128; s > 0; s >>= 1) {
        if (tid < s) {
#pragma unroll
            for (int r = 0; r < 4; ++r) {
                float va = sv[r][tid + s];
                int   ja = sj[r][tid + s];
                if (va > sv[r][tid] || (va == sv[r][tid] && ja < sj[r][tid])) {
                    sv[r][tid] = va; sj[r][tid] = ja;
                }
            }
        }
        __syncthreads();
    }

    if (tid < 4) {
        const int n = n0 + tid;
        const int idx = sj[tid][0];
        out[65536 + n] = (float)idx;
        atomicAdd(&g_hist[idx], 1);
        float zz[8];
#pragma unroll
        for (int d = 0; d < 8; ++d) {
            zz[d] = (tid == 0) ? z0[d] : (tid == 1) ? z1[d]
                  : (tid == 2) ? z2[d] : z3[d];
        }
        const float4* ep = (const float4*)(emb + idx * 8);
        float4 ea = ep[0], eb = ep[1];
        float e[8] = {ea.x, ea.y, ea.z, ea.w, eb.x, eb.y, eb.z, eb.w};
        const int b = n >> 10, r = n & 1023;
        float sq = 0.0f;
#pragma unroll
        for (int d = 0; d < 8; ++d) {
            out[b * 8192 + d * 1024 + r] = e[d];     // z_q (B,D,H,W)
            float diff = zz[d] - e[d];
            sq = fmaf(diff, diff, sq);
        }
        ssq[tid] = sq;
    }
    __syncthreads();
    if (tid == 0)
        atomicAdd(out + 73728, ssq[0] + ssq[1] + ssq[2] + ssq[3]);
}

// Kernel 2: single block, 1024 threads. Entropy/usage from g_hist;
// finalize commit from accumulated sum.
__global__ __launch_bounds__(1024) void gvq21_stats(float* __restrict__ out) {
    __shared__ float hred[1024];
    __shared__ int   ired[1024];
    const int tid = threadIdx.x;

    float h = 0.0f; int used = 0;
    for (int kk = tid; kk < NCODES; kk += 1024) {
        int c = g_hist[kk];
        float avg = (float)c * (1.0f / 8192.0f);
        h += avg * logf(avg + 1e-10f);               // accurate: 8 iters/thread
        used += (c > 0) ? 1 : 0;
    }
    hred[tid] = h; ired[tid] = used;
    __syncthreads();
    for (int t = 512; t > 0; t >>= 1) {
        if (tid < t) { hred[tid] += hred[tid + t]; ired[tid] += ired[tid + t]; }
        __syncthreads();
    }
    if (tid == 0) {
        float accum = out[73728];
        out[73728] = 0.25f * accum * (1.0f / 65536.0f);   // commit loss
        out[73729] = expf(-hred[0]);                      // perplexity
        out[73730] = (float)ired[0] * (1.0f / 8192.0f);   // usage
    }
}

extern "C" void kernel_launch(void* const* d_in, const int* in_sizes, int n_in,
                              void* d_out, int out_size, void* d_ws, size_t ws_size,
                              hipStream_t stream) {
    const float* z_e   = (const float*)d_in[0];
    const float* emb   = (const float*)d_in[1];
    const float* projw = (const float*)d_in[2];
    float* out = (float*)d_out;

    gvq21_init  <<<1,       1024, 0, stream>>>(out);
    gvq21_argmax<<<NBLOCKS, 256,  0, stream>>>(z_e, projw, emb, out);
    gvq21_stats <<<1,       1024, 0, stream>>>(out);
}